// Round 9
// baseline (284.082 us; speedup 1.0000x reference)
//
#include <hip/hip_runtime.h>
#include <hip/hip_cooperative_groups.h>

// Problem constants
#define NB 32768
#define NT 16
#define NV 32001   // V+1
#define NE 32
#define NTAGS 64

typedef __attribute__((ext_vector_type(8))) short short8;   // 8 bf16 (4 VGPR)
typedef __attribute__((ext_vector_type(4))) float f4;       // MFMA acc

#define MFMA16(a, b, c) __builtin_amdgcn_mfma_f32_16x16x32_bf16(a, b, c, 0, 0, 0)
// DS ops are in-order within a wave -> compiler-only fence suffices for same-wave LDS RAW
#define CFENCE() asm volatile("" ::: "memory")
#define LDSSYNC() asm volatile("s_waitcnt lgkmcnt(0)" ::: "memory")

namespace cg = cooperative_groups;

__device__ __forceinline__ float sigm_(float x) {
    return __builtin_amdgcn_rcpf(1.0f + __expf(-x));
}
__device__ __forceinline__ float tanh2_(float x) {  // 2*sigm(2x)-1
    float e = __expf(-2.0f * x);
    return fmaf(2.0f, __builtin_amdgcn_rcpf(1.0f + e), -1.0f);
}
__device__ __forceinline__ short f2bf(float x) {  // RNE float->bf16 bits
    union { float f; unsigned u; } v; v.f = x;
    unsigned r = v.u + 0x7fffu + ((v.u >> 16) & 1u);
    return (short)(r >> 16);
}
__device__ __forceinline__ short8 cvt8(f4 a, f4 b) {
    short8 r;
    r[0] = f2bf(a[0]); r[1] = f2bf(a[1]); r[2] = f2bf(a[2]); r[3] = f2bf(a[3]);
    r[4] = f2bf(b[0]); r[5] = f2bf(b[1]); r[6] = f2bf(b[2]); r[7] = f2bf(b[3]);
    return r;
}

// ---------------- prep body: blocks 0..31 classify (1024-row slabs), block 32 packs ----------------
__device__ __forceinline__ void prep_body(
    int b, int tid, const int* __restrict__ s,
    const float* __restrict__ Wih, const float* __restrict__ Whh,
    const float* __restrict__ bih, const float* __restrict__ bhh,
    const float* __restrict__ Wc, const float* __restrict__ Wt,
    short* __restrict__ wpack, short* __restrict__ wc1, short* __restrict__ wc2,
    short* __restrict__ wth, float* __restrict__ bsum,
    int* __restrict__ cH, int* __restrict__ listH, int* __restrict__ listL) {
    __shared__ int wbH[16], wbL[16];
    if (b < 32) {
        const int ln = tid & 63, wv = tid >> 6;
        unsigned long long mk[2]; bool hv[2];
#pragma unroll
        for (int it = 0; it < 2; ++it) {
            int row = b * 1024 + it * 512 + tid;
            hv[it] = s[row] >= 4;
            mk[it] = __ballot(hv[it]);
            if (ln == 0) wbH[it * 8 + wv] = __popcll(mk[it]);
        }
        __syncthreads();
        if (tid == 0) {
            int tH = 0, tL = 0;
#pragma unroll
            for (int i = 0; i < 16; ++i) {
                int ch = wbH[i];
                wbH[i] = tH; wbL[i] = tL;
                tH += ch; tL += 64 - ch;
            }
            cH[b] = tH;
        }
        __syncthreads();
        unsigned long long ltm = (1ull << ln) - 1ull;
#pragma unroll
        for (int it = 0; it < 2; ++it) {
            int row = b * 1024 + it * 512 + tid;
            if (hv[it]) listH[b * 1024 + wbH[it * 8 + wv] + __popcll(mk[it] & ltm)] = row;
            else        listL[b * 1024 + wbL[it * 8 + wv] + __popcll((~mk[it]) & ltm)] = row;
        }
    } else if (b == 32) {
        for (int t = tid; t < 18432; t += 512) {
            int r = t / 72, c = t % 72;
            wpack[t] = f2bf(c < 64 ? Whh[r * 64 + c] : 0.f);
        }
        for (int t = tid; t < 10240; t += 512) {
            int r = t / 40, c = t % 40;
            wpack[18432 + t] = f2bf(c < 32 ? Wih[r * 32 + c] : 0.f);
        }
        for (int t = tid; t < 1024; t += 512) { int r = t >> 5, c = t & 31; wc1[t] = f2bf(Wc[r * 96 + c]); }
        for (int t = tid; t < 2048; t += 512) { int r = t >> 6, c = t & 63; wc2[t] = f2bf(Wc[r * 96 + 32 + c]); }
        for (int t = tid; t < 2048; t += 512) { int r = t >> 5, c = t & 31; wth[t] = f2bf(Wt[r * 32 + c]); }
        if (tid < 256) bsum[tid] = bih[tid] + bhh[tid];
    }
}

// ---------------- main body: heavy (4 rows/wave, MFMA) + light (16 rows/iter, MFMA) ----------------
__device__ __forceinline__ void main_body(
    int blkId, int nBlocks, int tid,
    const int* __restrict__ x, const float* __restrict__ emb,
    const float* __restrict__ h0, const float* __restrict__ c0,
    const float* __restrict__ bc, const float* __restrict__ bt,
    const float* __restrict__ bsum,
    const short* __restrict__ wpack, const short* __restrict__ wc1,
    const short* __restrict__ wc2, const short* __restrict__ wth,
    const int* __restrict__ cH, const int* __restrict__ listH,
    const int* __restrict__ listL, float* __restrict__ out,
    short* sWhh, short* sHAall, short* sCmball, short* sC4all) {
    const int wave = tid >> 6, lane = tid & 63;
    const int q = lane >> 4, n = lane & 15;
    const int NW = nBlocks * 8;          // 4096
    const int gw = blkId * 8 + wave;

    // 32-slab prefix scan (per wave, shfl)
    int cs = (lane < 32) ? cH[lane] : 0;
    int v = cs;
#pragma unroll
    for (int o = 1; o < 32; o <<= 1) { int t2 = __shfl_up(v, o); if (lane >= o) v += t2; }
    const int vIncl = v, vExcl = v - cs;
    const int nH = __shfl(vIncl, 31);
    const int nL = NB - nH;
    const int liIncl = (lane + 1) * 1024 - vIncl;  // light prefixes (lane<32)
    const int liExcl = lane * 1024 - vExcl;
    const int nHW = (nH + 3) >> 2;                 // heavy wave count

    if (blkId * 8 < nHW) {  // block-uniform: only heavy blocks stage Whh (FULL 2304 uint4)
        for (int i = tid; i < 2304; i += 512)
            ((uint4*)sWhh)[i] = ((const uint4*)wpack)[i];
        __syncthreads();
    }

    if (gw < nHW) {
        short* hA = sHAall + wave * 1152;
        short* cmb = sCmball + wave * 640;
        short* c4 = sC4all + wave * 160;
        const short* wihG = wpack + 18432;

        short8 wihR[16];  // loop-invariant Wih fragments in registers
#pragma unroll
        for (int tl = 0; tl < 16; ++tl)
            wihR[tl] = *(const short8*)&wihG[(tl * 16 + n) * 40 + q * 8];

        float bias16[16];
#pragma unroll
        for (int tl = 0; tl < 16; ++tl) bias16[tl] = bsum[tl * 16 + n];
        float bc2[2] = {bc[n], bc[16 + n]};
        float bt4[4] = {bt[n], bt[16 + n], bt[32 + n], bt[48 + n]};
        float c0v[4]; short h0b[4];
#pragma unroll
        for (int u = 0; u < 4; ++u) { c0v[u] = c0[u * 16 + n]; h0b[u] = f2bf(h0[u * 16 + n]); }

        const f4 zero4 = {0.f, 0.f, 0.f, 0.f};
        f4 acc[16];
        float cst[4][4];

        auto initSt = [&]() {
#pragma unroll
            for (int u = 0; u < 4; ++u) {
                short hb = h0b[u];
#pragma unroll
                for (int r = 0; r < 4; ++r) {
                    cst[r][u] = c0v[u];
                    hA[(q * 4 + r) * 72 + u * 16 + n] = hb;
                }
            }
            CFENCE();
        };
        auto doStep = [&](short8 aP, bool doRelu) {
            short8 ah0 = *(const short8*)&hA[n * 72 + q * 8];
            short8 ah1 = *(const short8*)&hA[n * 72 + 32 + q * 8];
#pragma unroll
            for (int tl = 0; tl < 16; ++tl) acc[tl] = MFMA16(aP, wihR[tl], zero4);
#pragma unroll
            for (int tl = 0; tl < 16; ++tl) {
                const short* rbp = &sWhh[(tl * 16 + n) * 72 + q * 8];
                f4 t0 = acc[tl];
                t0 = MFMA16(ah0, *(const short8*)rbp, t0);
                t0 = MFMA16(ah1, *(const short8*)(rbp + 32), t0);
                acc[tl] = t0;
            }
            CFENCE();
#pragma unroll
            for (int u = 0; u < 4; ++u)
#pragma unroll
                for (int r = 0; r < 4; ++r) {
                    float ip = acc[u][r] + bias16[u];
                    float fp = acc[4 + u][r] + bias16[4 + u];
                    float gp = acc[8 + u][r] + bias16[8 + u];
                    float op = acc[12 + u][r] + bias16[12 + u];
                    float cc = fmaf(sigm_(fp), cst[r][u], sigm_(ip) * tanh2_(gp));
                    cst[r][u] = cc;
                    float hh = sigm_(op) * tanh2_(cc);
                    if (doRelu) hh = fmaxf(hh, 0.f);
                    hA[(q * 4 + r) * 72 + u * 16 + n] = f2bf(hh);
                }
            CFENCE();
        };
        auto combMM = [&](short8 aroot, short* dst, int strideSel) {
            short8 lh0 = *(const short8*)&hA[n * 72 + q * 8];
            short8 lh1 = *(const short8*)&hA[n * 72 + 32 + q * 8];
#pragma unroll
            for (int tl2 = 0; tl2 < 2; ++tl2) {
                float bv = bc2[tl2];
                f4 t0 = {bv, bv, bv, bv};
                short8 b1 = *(const short8*)&wc1[(tl2 * 16 + n) * 32 + q * 8];
                t0 = MFMA16(aroot, b1, t0);
                const short* rbp = &wc2[(tl2 * 16 + n) * 64 + q * 8];
                t0 = MFMA16(lh0, *(const short8*)rbp, t0);
                t0 = MFMA16(lh1, *(const short8*)(rbp + 32), t0);
#pragma unroll
                for (int r = 0; r < 4; ++r) {
                    int ui = strideSel ? (q * 4 + r) : r;
                    dst[ui * 40 + tl2 * 16 + n] = f2bf(fmaxf(t0[r], 0.f));
                }
            }
            CFENCE();
        };

#pragma unroll 1
        for (int it = gw; it * 4 < nH; it += NW) {
            const int base = it * 4;
            int idxq = min(base + q, nH - 1);
            int sl = 0;
#pragma unroll
            for (int b2 = 0; b2 < 32; ++b2) sl += (__shfl(vIncl, b2) <= idxq) ? 1 : 0;
            const int row = listH[sl * 1024 + idxq - __shfl(vExcl, sl)];
            const int tokAll = x[row * 16 + n];
            const int liBase = (n & 3) * 16 + (n >> 2) * 4;

            // ---- phase 1: 4 rows x 4 nodes, 4 steps (emb gathered fp32, converted) ----
            initSt();
            int tok = __shfl(tokAll, liBase);
            {
                const f4* ep = (const f4*)&emb[tok * 32 + q * 8];
                f4 e0 = ep[0], e1 = ep[1];
                short8 aNext = cvt8(e0, e1);
                const short8 aRoot = aNext;
#pragma unroll 1
                for (int t = 0; t < 4; ++t) {
                    short8 aP = aNext;
                    f4 p0, p1;
                    if (t < 3) {
                        int tk2 = __shfl(tokAll, liBase + t + 1);
                        const f4* ep2 = (const f4*)&emb[tk2 * 32 + q * 8];
                        p0 = ep2[0]; p1 = ep2[1];   // loads in flight across doStep
                    }
                    doStep(aP, t == 3);
                    if (t < 3) aNext = cvt8(p0, p1);
                }
                combMM(aRoot, cmb, 1);
            }

            // ---- phase 2: node 4 (children = comb_0..3), rows duplicated x4 ----
            initSt();
            int tokR = __shfl(tokAll, (n & 3) * 16);
            short8 aR4;
            {
                const f4* ep = (const f4*)&emb[tokR * 32 + q * 8];
                aR4 = cvt8(ep[0], ep[1]);
            }
#pragma unroll 1
            for (int t = 0; t < 4; ++t) {
                short8 aC = *(const short8*)&cmb[(t * 4 + (n & 3)) * 40 + q * 8];
                doStep(aC, t == 3);
            }
            combMM(aR4, c4, 0);

            // ---- phase 3: logits + log_softmax for 4 rows ----
            short8 cA = *(const short8*)&c4[(n & 3) * 40 + q * 8];
            f4 a3[4];
#pragma unroll
            for (int tl3 = 0; tl3 < 4; ++tl3) {
                float bv = bt4[tl3];
                f4 t0 = {bv, bv, bv, bv};
                short8 bW = *(const short8*)&wth[(tl3 * 16 + n) * 32 + q * 8];
                a3[tl3] = MFMA16(cA, bW, t0);
            }
#pragma unroll
            for (int r = 0; r < 4; ++r) {
                float l0 = a3[0][r], l1 = a3[1][r], l2 = a3[2][r], l3 = a3[3][r];
                float mx = fmaxf(fmaxf(l0, l1), fmaxf(l2, l3));
#pragma unroll
                for (int o2 = 8; o2; o2 >>= 1) mx = fmaxf(mx, __shfl_xor(mx, o2));
                float sm = __expf(l0 - mx) + __expf(l1 - mx) +
                           __expf(l2 - mx) + __expf(l3 - mx);
#pragma unroll
                for (int o2 = 8; o2; o2 >>= 1) sm += __shfl_xor(sm, o2);
                float lse = mx + __logf(sm);
                if (q == r && base + r < nH) {
                    out[row * 64 + n] = l0 - lse;
                    out[row * 64 + 16 + n] = l1 - lse;
                    out[row * 64 + 32 + n] = l2 - lse;
                    out[row * 64 + 48 + n] = l3 - lse;
                }
            }
        }
    }

    // ---- light rows: 16 rows/iteration via MFMA; reverse wave order (no double duty) ----
    if (nL > 0) {
        short* cmbL = sCmball + wave * 640;
        f4 bcV[2], btV[4];
#pragma unroll
        for (int t = 0; t < 2; ++t) { float bv = bc[t * 16 + n]; bcV[t] = f4{bv, bv, bv, bv}; }
#pragma unroll
        for (int t = 0; t < 4; ++t) { float bv = bt[t * 16 + n]; btV[t] = f4{bv, bv, bv, bv}; }
        const int lgw = NW - 1 - gw;
#pragma unroll 1
        for (int base = lgw * 16; base < nL; base += NW * 16) {
            int idx = min(base + lane, nL - 1);
            int sl = 0;
#pragma unroll
            for (int b2 = 0; b2 < 32; ++b2) sl += (__shfl(liIncl, b2) <= idx) ? 1 : 0;
            const int lrow = listL[sl * 1024 + idx - __shfl(liExcl, sl)];
            const int ltok = x[lrow * 16];
            int t8 = __shfl(ltok, n);
            const f4* ep = (const f4*)&emb[t8 * 32 + q * 8];
            short8 aE = cvt8(ep[0], ep[1]);
            // comb = relu(emb @ Wc1^T + bc) -> LDS [16][40]
#pragma unroll
            for (int tl2 = 0; tl2 < 2; ++tl2) {
                short8 b1 = *(const short8*)&wc1[(tl2 * 16 + n) * 32 + q * 8];
                f4 t0 = MFMA16(aE, b1, bcV[tl2]);
#pragma unroll
                for (int r = 0; r < 4; ++r)
                    cmbL[(q * 4 + r) * 40 + tl2 * 16 + n] = f2bf(fmaxf(t0[r], 0.f));
            }
            CFENCE();
            short8 cA = *(const short8*)&cmbL[n * 40 + q * 8];
            f4 a3[4];
#pragma unroll
            for (int tl3 = 0; tl3 < 4; ++tl3) {
                short8 bW = *(const short8*)&wth[(tl3 * 16 + n) * 32 + q * 8];
                a3[tl3] = MFMA16(cA, bW, btV[tl3]);
            }
#pragma unroll
            for (int r = 0; r < 4; ++r) {
                float l0 = a3[0][r], l1 = a3[1][r], l2 = a3[2][r], l3 = a3[3][r];
                float mx = fmaxf(fmaxf(l0, l1), fmaxf(l2, l3));
#pragma unroll
                for (int o2 = 8; o2; o2 >>= 1) mx = fmaxf(mx, __shfl_xor(mx, o2));
                float sm = __expf(l0 - mx) + __expf(l1 - mx) +
                           __expf(l2 - mx) + __expf(l3 - mx);
#pragma unroll
                for (int o2 = 8; o2; o2 >>= 1) sm += __shfl_xor(sm, o2);
                float lse = mx + __logf(sm);
                int rowO = __shfl(lrow, q * 4 + r);
                if (base + q * 4 + r < nL) {
                    out[rowO * 64 + n] = l0 - lse;
                    out[rowO * 64 + 16 + n] = l1 - lse;
                    out[rowO * 64 + 32 + n] = l2 - lse;
                    out[rowO * 64 + 48 + n] = l3 - lse;
                }
            }
            CFENCE();
        }
    }
}

// ---------------- fused cooperative kernel: prep -> grid sync -> main ----------------
__global__ __launch_bounds__(512, 4) void fused_all(
    const int* x, const int* s, const float* emb, const float* Wih, const float* Whh,
    const float* bih, const float* bhh, const float* h0, const float* c0,
    const float* Wc, const float* bc, const float* Wt, const float* bt,
    short* wpack, short* wc1, short* wc2, short* wth, float* bsum,
    int* cH, int* listH, int* listL, float* out) {
    __shared__ __align__(16) short sWhh[18432];
    __shared__ __align__(16) short sHA[8 * 1152];
    __shared__ __align__(16) short sCmb[8 * 640];
    __shared__ __align__(16) short sC4[8 * 160];
    prep_body(blockIdx.x, threadIdx.x, s, Wih, Whh, bih, bhh, Wc, Wt,
              wpack, wc1, wc2, wth, bsum, cH, listH, listL);
    cg::this_grid().sync();
    main_body(blockIdx.x, gridDim.x, threadIdx.x, x, emb, h0, c0, bc, bt, bsum,
              wpack, wc1, wc2, wth, cH, listH, listL, out, sWhh, sHA, sCmb, sC4);
}

// ---------------- non-cooperative fallback pair (same bodies) ----------------
__global__ __launch_bounds__(512) void prep_kernel(
    const int* s, const float* Wih, const float* Whh, const float* bih,
    const float* bhh, const float* Wc, const float* Wt,
    short* wpack, short* wc1, short* wc2, short* wth, float* bsum,
    int* cH, int* listH, int* listL) {
    prep_body(blockIdx.x, threadIdx.x, s, Wih, Whh, bih, bhh, Wc, Wt,
              wpack, wc1, wc2, wth, bsum, cH, listH, listL);
}
__global__ __launch_bounds__(512, 4) void main_kernel(
    const int* x, const float* emb, const float* h0, const float* c0,
    const float* bc, const float* bt, const float* bsum,
    const short* wpack, const short* wc1, const short* wc2, const short* wth,
    const int* cH, const int* listH, const int* listL, float* out) {
    __shared__ __align__(16) short sWhh[18432];
    __shared__ __align__(16) short sHA[8 * 1152];
    __shared__ __align__(16) short sCmb[8 * 640];
    __shared__ __align__(16) short sC4[8 * 160];
    main_body(blockIdx.x, gridDim.x, threadIdx.x, x, emb, h0, c0, bc, bt, bsum,
              wpack, wc1, wc2, wth, cH, listH, listL, out, sWhh, sHA, sCmb, sC4);
}

// ---------------- fallback (small ws): monolithic fp32 kernel ----------------
__global__ __launch_bounds__(512) void tagger_fallback(
    const int* __restrict__ x, const int* __restrict__ s, const float* __restrict__ emb,
    const float* __restrict__ Wih, const float* __restrict__ Whh,
    const float* __restrict__ bih, const float* __restrict__ bhh,
    const float* __restrict__ h0, const float* __restrict__ c0,
    const float* __restrict__ Wc, const float* __restrict__ bc,
    const float* __restrict__ Wt, const float* __restrict__ bt,
    float* __restrict__ out) {
    __shared__ float4 WhhP[4096];
    __shared__ float combBuf[8][128];
    for (int i = threadIdx.x; i < 4096; i += 512) {
        int k = i & 63, jj = i >> 6;
        WhhP[k * 64 + jj] = make_float4(Whh[jj * 64 + k], Whh[(jj + 64) * 64 + k],
                                        Whh[(jj + 128) * 64 + k], Whh[(jj + 192) * 64 + k]);
    }
    __syncthreads();
    const int wave = threadIdx.x >> 6, j = threadIdx.x & 63, jm = j & 31;
    const int b = blockIdx.x * 8 + wave;
    const int sv = s[b];
    const int* xb = x + b * NT;
    const float bcj = bc[jm];
    auto rc_val = [&](int tok) -> float {
        float r = 0.f;
#pragma unroll
        for (int k = 0; k < 32; ++k) r = fmaf(emb[tok * NE + k], Wc[jm * 96 + k], r);
        return r;
    };
    float comb4;
    if (sv >= 4) {
        const float h0j = h0[j], c0j = c0[j];
        float4 bsj = make_float4(bih[j] + bhh[j], bih[j + 64] + bhh[j + 64],
                                 bih[j + 128] + bhh[j + 128], bih[j + 192] + bhh[j + 192]);
#pragma unroll 1
        for (int node = 0; node < 4; ++node) {
            float h = h0j, c = c0j;
#pragma unroll 1
            for (int t = 0; t < 4; ++t) {
                int tok = xb[node * 4 + t];
                float4 p = bsj;
#pragma unroll
                for (int k = 0; k < 32; ++k) {
                    float e = emb[tok * NE + k];
                    p.x = fmaf(e, Wih[j * 32 + k], p.x);
                    p.y = fmaf(e, Wih[(j + 64) * 32 + k], p.y);
                    p.z = fmaf(e, Wih[(j + 128) * 32 + k], p.z);
                    p.w = fmaf(e, Wih[(j + 192) * 32 + k], p.w);
                }
                float4 a = make_float4(0.f, 0.f, 0.f, 0.f);
#pragma unroll
                for (int k = 0; k < 64; ++k) {
                    float hk = __shfl(h, k);
                    float4 w = WhhP[k * 64 + j];
                    a.x = fmaf(hk, w.x, a.x); a.y = fmaf(hk, w.y, a.y);
                    a.z = fmaf(hk, w.z, a.z); a.w = fmaf(hk, w.w, a.w);
                }
                a.x += p.x; a.y += p.y; a.z += p.z; a.w += p.w;
                float ig = sigm_(a.x), fg = sigm_(a.y), gg = tanh2_(a.z), og = sigm_(a.w);
                c = fmaf(fg, c, ig * gg);
                h = og * tanh2_(c);
            }
            float last = fmaxf(h, 0.f);
            float acc = rc_val(xb[node * 4]) + bcj;
#pragma unroll
            for (int k = 0; k < 64; ++k)
                acc = fmaf(__shfl(last, k), Wc[jm * 96 + 32 + k], acc);
            if (j < 32) combBuf[wave][node * 32 + j] = fmaxf(acc, 0.f);
        }
        LDSSYNC();
        float h = h0j, c = c0j;
#pragma unroll 1
        for (int t = 0; t < 4; ++t) {
            float4 a = make_float4(0.f, 0.f, 0.f, 0.f);
#pragma unroll
            for (int k = 0; k < 32; ++k) {
                float ck = combBuf[wave][t * 32 + k];
                a.x = fmaf(ck, Wih[j * 32 + k], a.x);
                a.y = fmaf(ck, Wih[(j + 64) * 32 + k], a.y);
                a.z = fmaf(ck, Wih[(j + 128) * 32 + k], a.z);
                a.w = fmaf(ck, Wih[(j + 192) * 32 + k], a.w);
            }
#pragma unroll
            for (int k = 0; k < 64; ++k) {
                float hk = __shfl(h, k);
                float4 w = WhhP[k * 64 + j];
                a.x = fmaf(hk, w.x, a.x); a.y = fmaf(hk, w.y, a.y);
                a.z = fmaf(hk, w.z, a.z); a.w = fmaf(hk, w.w, a.w);
            }
            a.x += bih[j] + bhh[j]; a.y += bih[j + 64] + bhh[j + 64];
            a.z += bih[j + 128] + bhh[j + 128]; a.w += bih[j + 192] + bhh[j + 192];
            float ig = sigm_(a.x), fg = sigm_(a.y), gg = tanh2_(a.z), og = sigm_(a.w);
            c = fmaf(fg, c, ig * gg);
            h = og * tanh2_(c);
        }
        float last = fmaxf(h, 0.f);
        float acc = rc_val(xb[0]) + bcj;
#pragma unroll
        for (int k = 0; k < 64; ++k)
            acc = fmaf(__shfl(last, k), Wc[jm * 96 + 32 + k], acc);
        comb4 = fmaxf(acc, 0.f);
    } else {
        comb4 = fmaxf(rc_val(xb[0]) + bcj, 0.f);
    }
    float logit = bt[j];
    const float* wtr = Wt + j * 32;
#pragma unroll
    for (int k = 0; k < 32; ++k) logit = fmaf(__shfl(comb4, k), wtr[k], logit);
    float mx = logit;
#pragma unroll
    for (int off = 32; off; off >>= 1) mx = fmaxf(mx, __shfl_xor(mx, off));
    float ex = __expf(logit - mx);
    float sum = ex;
#pragma unroll
    for (int off = 32; off; off >>= 1) sum += __shfl_xor(sum, off);
    out[b * 64 + j] = logit - mx - __logf(sum);
}

extern "C" void kernel_launch(void* const* d_in, const int* in_sizes, int n_in,
                              void* d_out, int out_size, void* d_ws, size_t ws_size,
                              hipStream_t stream) {
    const int* x = (const int*)d_in[0];
    const int* s = (const int*)d_in[1];
    const float* emb = (const float*)d_in[2];
    const float* Wih = (const float*)d_in[3];
    const float* Whh = (const float*)d_in[4];
    const float* bih = (const float*)d_in[5];
    const float* bhh = (const float*)d_in[6];
    const float* h0 = (const float*)d_in[7];
    const float* c0 = (const float*)d_in[8];
    const float* Wc = (const float*)d_in[9];
    const float* bc = (const float*)d_in[10];
    const float* Wt = (const float*)d_in[11];
    const float* bt = (const float*)d_in[12];
    float* out = (float*)d_out;

    auto al16 = [](size_t v) { return (v + 15) & ~(size_t)15; };
    size_t off = 0;
    size_t oWpack = off; off = al16(off + (size_t)28672 * 2);
    size_t oWc1 = off;   off = al16(off + 1024 * 2);
    size_t oWc2 = off;   off = al16(off + 2048 * 2);
    size_t oWt = off;    off = al16(off + 2048 * 2);
    size_t oBsum = off;  off = al16(off + 256 * 4);
    size_t oCH = off;    off = al16(off + 32 * 4);
    size_t oListH = off; off = al16(off + (size_t)NB * 4);
    size_t oListL = off; off = al16(off + (size_t)NB * 4);
    size_t need = off;

    char* ws = (char*)d_ws;
    if (ws_size >= need) {
        short* wpack = (short*)(ws + oWpack);
        short* wc1 = (short*)(ws + oWc1);
        short* wc2 = (short*)(ws + oWc2);
        short* wth = (short*)(ws + oWt);
        float* bsum = (float*)(ws + oBsum);
        int* cHp = (int*)(ws + oCH);
        int* listH = (int*)(ws + oListH);
        int* listL = (int*)(ws + oListL);

        void* kargs[] = {
            (void*)&x, (void*)&s, (void*)&emb, (void*)&Wih, (void*)&Whh,
            (void*)&bih, (void*)&bhh, (void*)&h0, (void*)&c0, (void*)&Wc,
            (void*)&bc, (void*)&Wt, (void*)&bt,
            (void*)&wpack, (void*)&wc1, (void*)&wc2, (void*)&wth, (void*)&bsum,
            (void*)&cHp, (void*)&listH, (void*)&listL, (void*)&out};
        hipError_t e = hipLaunchCooperativeKernel((const void*)fused_all, dim3(512),
                                                  dim3(512), kargs, 0, stream);
        if (e != hipSuccess) {
            (void)hipGetLastError();  // clear sticky error, use 2-kernel path
            prep_kernel<<<dim3(33), dim3(512), 0, stream>>>(
                s, Wih, Whh, bih, bhh, Wc, Wt, wpack, wc1, wc2, wth, bsum,
                cHp, listH, listL);
            main_kernel<<<dim3(512), dim3(512), 0, stream>>>(
                x, emb, h0, c0, bc, bt, bsum, wpack, wc1, wc2, wth,
                cHp, listH, listL, out);
        }
    } else {
        tagger_fallback<<<dim3(4096), dim3(512), 0, stream>>>(
            x, s, emb, Wih, Whh, bih, bhh, h0, c0, Wc, bc, Wt, bt, out);
    }
}

// Round 10
// 264.018 us; speedup vs baseline: 1.0760x; 1.0760x over previous
//
#include <hip/hip_runtime.h>

// Problem constants
#define NB 32768
#define NT 16
#define NV 32001   // V+1
#define NE 32
#define NTAGS 64

typedef __attribute__((ext_vector_type(8))) short short8;   // 8 bf16 (4 VGPR)
typedef __attribute__((ext_vector_type(4))) float f4;       // MFMA acc

#define MFMA16(a, b, c) __builtin_amdgcn_mfma_f32_16x16x32_bf16(a, b, c, 0, 0, 0)
// DS ops are in-order within a wave -> compiler-only fence suffices for same-wave LDS RAW
#define CFENCE() asm volatile("" ::: "memory")
#define LDSSYNC() asm volatile("s_waitcnt lgkmcnt(0)" ::: "memory")

__device__ __forceinline__ float sigm_(float x) {
    return __builtin_amdgcn_rcpf(1.0f + __expf(-x));
}
__device__ __forceinline__ float tanh2_(float x) {  // 2*sigm(2x)-1
    float e = __expf(-2.0f * x);
    return fmaf(2.0f, __builtin_amdgcn_rcpf(1.0f + e), -1.0f);
}
__device__ __forceinline__ short f2bf(float x) {  // RNE float->bf16 bits
    union { float f; unsigned u; } v; v.f = x;
    unsigned r = v.u + 0x7fffu + ((v.u >> 16) & 1u);
    return (short)(r >> 16);
}
__device__ __forceinline__ short8 cvt8(f4 a, f4 b) {
    short8 r;
    r[0] = f2bf(a[0]); r[1] = f2bf(a[1]); r[2] = f2bf(a[2]); r[3] = f2bf(a[3]);
    r[4] = f2bf(b[0]); r[5] = f2bf(b[1]); r[6] = f2bf(b[2]); r[7] = f2bf(b[3]);
    return r;
}

// ---------------- K1: blocks 0..31 classify (1024-row slabs, no atomics); block 32 packs ----------
__global__ __launch_bounds__(512) void prep_kernel(
    const int* __restrict__ s,
    const float* __restrict__ Wih, const float* __restrict__ Whh,
    const float* __restrict__ bih, const float* __restrict__ bhh,
    const float* __restrict__ Wc, const float* __restrict__ Wt,
    short* __restrict__ wpack, short* __restrict__ wc1, short* __restrict__ wc2,
    short* __restrict__ wth, float* __restrict__ bsum,
    int* __restrict__ cH, int* __restrict__ listH, int* __restrict__ listL) {
    __shared__ int wbH[16], wbL[16];
    const int tid = threadIdx.x, b = blockIdx.x;
    if (b < 32) {
        const int ln = tid & 63, wv = tid >> 6;
        unsigned long long mk[2]; bool hv[2];
#pragma unroll
        for (int it = 0; it < 2; ++it) {
            int row = b * 1024 + it * 512 + tid;
            hv[it] = s[row] >= 4;
            mk[it] = __ballot(hv[it]);
            if (ln == 0) wbH[it * 8 + wv] = __popcll(mk[it]);
        }
        __syncthreads();
        if (tid == 0) {
            int tH = 0, tL = 0;
#pragma unroll
            for (int i = 0; i < 16; ++i) {
                int ch = wbH[i];
                wbH[i] = tH; wbL[i] = tL;
                tH += ch; tL += 64 - ch;
            }
            cH[b] = tH;
        }
        __syncthreads();
        unsigned long long ltm = (1ull << ln) - 1ull;
#pragma unroll
        for (int it = 0; it < 2; ++it) {
            int row = b * 1024 + it * 512 + tid;
            if (hv[it]) listH[b * 1024 + wbH[it * 8 + wv] + __popcll(mk[it] & ltm)] = row;
            else        listL[b * 1024 + wbL[it * 8 + wv] + __popcll((~mk[it]) & ltm)] = row;
        }
    } else {  // b == 32: weight pack
        for (int t = tid; t < 18432; t += 512) {
            int r = t / 72, c = t % 72;
            wpack[t] = f2bf(c < 64 ? Whh[r * 64 + c] : 0.f);
        }
        for (int t = tid; t < 10240; t += 512) {
            int r = t / 40, c = t % 40;
            wpack[18432 + t] = f2bf(c < 32 ? Wih[r * 32 + c] : 0.f);
        }
        for (int t = tid; t < 1024; t += 512) { int r = t >> 5, c = t & 31; wc1[t] = f2bf(Wc[r * 96 + c]); }
        for (int t = tid; t < 2048; t += 512) { int r = t >> 6, c = t & 63; wc2[t] = f2bf(Wc[r * 96 + 32 + c]); }
        for (int t = tid; t < 2048; t += 512) { int r = t >> 5, c = t & 31; wth[t] = f2bf(Wt[r * 32 + c]); }
        if (tid < 256) bsum[tid] = bih[tid] + bhh[tid];
    }
}

// ---------------- K2: main — heavy (2 rows/wave => 4096 chains) + light (16 rows/iter MFMA) ------
__global__ __launch_bounds__(256, 3) void main_kernel(
    const int* __restrict__ x, const float* __restrict__ emb,
    const float* __restrict__ h0, const float* __restrict__ c0,
    const float* __restrict__ bc, const float* __restrict__ bt,
    const float* __restrict__ bsum,
    const short* __restrict__ wpack, const short* __restrict__ wc1,
    const short* __restrict__ wc2, const short* __restrict__ wth,
    const int* __restrict__ cH, const int* __restrict__ listH,
    const int* __restrict__ listL, float* __restrict__ out) {
    __shared__ __align__(16) short sWhh[18432];      // 36 KB [256][72] bf16 (FULL 2304 uint4)
    __shared__ __align__(16) short sHA[4 * 1152];    // per-wave h, A-frag layout [16 units][72]
    __shared__ __align__(16) short sCmb[4 * 640];    // per-wave comb[(node*2+row)][40] / light comb
    __shared__ __align__(16) short sC4[4 * 160];     // per-wave comb4[row][40]

    const int tid = threadIdx.x, wave = tid >> 6, lane = tid & 63;
    const int q = lane >> 4, n = lane & 15;
    const int NW = gridDim.x * 4;   // 4096
    const int gw = blockIdx.x * 4 + wave;

    // 32-slab prefix scan (per wave, shfl)
    int cs = (lane < 32) ? cH[lane] : 0;
    int v = cs;
#pragma unroll
    for (int o = 1; o < 32; o <<= 1) { int t2 = __shfl_up(v, o); if (lane >= o) v += t2; }
    const int vIncl = v, vExcl = v - cs;
    const int nH = __shfl(vIncl, 31);
    const int nL = NB - nH;
    const int liIncl = (lane + 1) * 1024 - vIncl;  // light prefixes (lane<32)
    const int liExcl = lane * 1024 - vExcl;
    const int nHW = (nH + 1) >> 1;                 // heavy wave count (2 rows/wave)

    if ((int)blockIdx.x * 4 < nHW) {  // block-uniform: only heavy blocks stage Whh
        for (int i = tid; i < 2304; i += 256)
            ((uint4*)sWhh)[i] = ((const uint4*)wpack)[i];
        __syncthreads();
    }

    if (gw < nHW) {
        short* hA = sHA + wave * 1152;
        short* cmb = sCmb + wave * 640;
        short* c4 = sC4 + wave * 160;
        const short* wihG = wpack + 18432;

        short8 wihR[16];  // loop-invariant Wih fragments in registers
#pragma unroll
        for (int tl = 0; tl < 16; ++tl)
            wihR[tl] = *(const short8*)&wihG[(tl * 16 + n) * 40 + q * 8];

        float bias16[16];
#pragma unroll
        for (int tl = 0; tl < 16; ++tl) bias16[tl] = bsum[tl * 16 + n];
        float bc2[2] = {bc[n], bc[16 + n]};
        float bt4[4] = {bt[n], bt[16 + n], bt[32 + n], bt[48 + n]};
        float c0v[4]; short h0b[4];
#pragma unroll
        for (int u = 0; u < 4; ++u) { c0v[u] = c0[u * 16 + n]; h0b[u] = f2bf(h0[u * 16 + n]); }

        const f4 zero4 = {0.f, 0.f, 0.f, 0.f};
        f4 acc[16];
        float cst[4][4];

        auto initSt = [&]() {
#pragma unroll
            for (int u = 0; u < 4; ++u) {
                short hb = h0b[u];
#pragma unroll
                for (int r = 0; r < 4; ++r) {
                    cst[r][u] = c0v[u];
                    hA[(q * 4 + r) * 72 + u * 16 + n] = hb;
                }
            }
            CFENCE();
        };
        // One LSTM step for all 16 unit-slots. guardP1: phase-1 stores only for real
        // units 0..7 (q<2); ghost rows 8..15 stay at h0 (deterministic).
        auto doStep = [&](short8 aP, bool doRelu, bool guardP1) {
            short8 ah0 = *(const short8*)&hA[n * 72 + q * 8];
            short8 ah1 = *(const short8*)&hA[n * 72 + 32 + q * 8];
#pragma unroll
            for (int tl = 0; tl < 16; ++tl) acc[tl] = MFMA16(aP, wihR[tl], zero4);
#pragma unroll
            for (int tl = 0; tl < 16; ++tl) {
                const short* rbp = &sWhh[(tl * 16 + n) * 72 + q * 8];
                f4 t0 = acc[tl];
                t0 = MFMA16(ah0, *(const short8*)rbp, t0);
                t0 = MFMA16(ah1, *(const short8*)(rbp + 32), t0);
                acc[tl] = t0;
            }
            CFENCE();
#pragma unroll
            for (int u = 0; u < 4; ++u)
#pragma unroll
                for (int r = 0; r < 4; ++r) {
                    float ip = acc[u][r] + bias16[u];
                    float fp = acc[4 + u][r] + bias16[4 + u];
                    float gp = acc[8 + u][r] + bias16[8 + u];
                    float op = acc[12 + u][r] + bias16[12 + u];
                    float cc = fmaf(sigm_(fp), cst[r][u], sigm_(ip) * tanh2_(gp));
                    cst[r][u] = cc;
                    float hh = sigm_(op) * tanh2_(cc);
                    if (doRelu) hh = fmaxf(hh, 0.f);
                    if (!guardP1 || q < 2)
                        hA[(q * 4 + r) * 72 + u * 16 + n] = f2bf(hh);
                }
            CFENCE();
        };
        // comb = relu([root,last]@Wc^T+bc). mode 0 (phase1): store units 0..7 (q<2) at
        // dst[unit*40]; mode 1 (phase2): rows duplicated -> store rows 0..1 from q==0.
        auto combMM = [&](short8 aroot, short* dst, int mode) {
            short8 lh0 = *(const short8*)&hA[n * 72 + q * 8];
            short8 lh1 = *(const short8*)&hA[n * 72 + 32 + q * 8];
#pragma unroll
            for (int tl2 = 0; tl2 < 2; ++tl2) {
                float bv = bc2[tl2];
                f4 t0 = {bv, bv, bv, bv};
                short8 b1 = *(const short8*)&wc1[(tl2 * 16 + n) * 32 + q * 8];
                t0 = MFMA16(aroot, b1, t0);
                const short* rbp = &wc2[(tl2 * 16 + n) * 64 + q * 8];
                t0 = MFMA16(lh0, *(const short8*)rbp, t0);
                t0 = MFMA16(lh1, *(const short8*)(rbp + 32), t0);
#pragma unroll
                for (int r = 0; r < 4; ++r) {
                    if (mode == 0) {
                        if (q < 2)
                            dst[(q * 4 + r) * 40 + tl2 * 16 + n] = f2bf(fmaxf(t0[r], 0.f));
                    } else {
                        if (q == 0 && r < 2)
                            dst[r * 40 + tl2 * 16 + n] = f2bf(fmaxf(t0[r], 0.f));
                    }
                }
            }
            CFENCE();
        };

#pragma unroll 1
        for (int it = gw; it * 2 < nH; it += NW) {
            const int base = it * 2;
            const int rsel = (lane >> 4) & 1;            // lanes 0-15: row0, 16-31: row1, dup
            int idxq = min(base + rsel, nH - 1);
            int sl = 0;
#pragma unroll
            for (int b2 = 0; b2 < 32; ++b2) sl += (__shfl(vIncl, b2) <= idxq) ? 1 : 0;
            const int rowv = listH[sl * 1024 + idxq - __shfl(vExcl, sl)];
            const int tokAll = x[rowv * 16 + (lane & 15)];  // lane holds x[row_rsel][lane&15]
            const int m7 = n & 7;                           // unit (ghosts mirror 0..7)
            const int liBase = (m7 & 1) * 16 + (m7 >> 1) * 4;  // unit: row=m7&1, node=m7>>1

            // ---- phase 1: 2 rows x 4 nodes in units 0..7 (8 ghosts), 4 steps ----
            initSt();
            int tok = __shfl(tokAll, liBase);
            {
                const f4* ep = (const f4*)&emb[tok * 32 + q * 8];
                f4 e0 = ep[0], e1 = ep[1];
                short8 aNext = cvt8(e0, e1);
                const short8 aRoot = aNext;
#pragma unroll 1
                for (int t = 0; t < 4; ++t) {
                    short8 aP = aNext;
                    f4 p0, p1;
                    if (t < 3) {
                        int tk2 = __shfl(tokAll, liBase + t + 1);
                        const f4* ep2 = (const f4*)&emb[tk2 * 32 + q * 8];
                        p0 = ep2[0]; p1 = ep2[1];   // loads in flight across doStep
                    }
                    doStep(aP, t == 3, true);
                    if (t < 3) aNext = cvt8(p0, p1);
                }
                combMM(aRoot, cmb, 0);   // cmb[(node*2+row)][40]
            }

            // ---- phase 2: node 4 (children = comb_0..3), 2 rows duplicated x8 ----
            initSt();
            int tokR = __shfl(tokAll, (n & 1) * 16);     // x[row_{n&1}][0]
            short8 aR4;
            {
                const f4* ep = (const f4*)&emb[tokR * 32 + q * 8];
                aR4 = cvt8(ep[0], ep[1]);
            }
#pragma unroll 1
            for (int t = 0; t < 4; ++t) {
                short8 aC = *(const short8*)&cmb[(t * 2 + (n & 1)) * 40 + q * 8];
                doStep(aC, t == 3, false);               // all unit-slots hold valid dups
            }
            combMM(aR4, c4, 1);                          // c4[row][40], rows 0..1

            // ---- phase 3: logits + log_softmax for 2 rows ----
            short8 cA = *(const short8*)&c4[(n & 1) * 40 + q * 8];
            f4 a3[4];
#pragma unroll
            for (int tl3 = 0; tl3 < 4; ++tl3) {
                float bv = bt4[tl3];
                f4 t0 = {bv, bv, bv, bv};
                short8 bW = *(const short8*)&wth[(tl3 * 16 + n) * 32 + q * 8];
                a3[tl3] = MFMA16(cA, bW, t0);
            }
#pragma unroll
            for (int r = 0; r < 2; ++r) {                // D row m => row m&1; r=0,1 suffice
                float l0 = a3[0][r], l1 = a3[1][r], l2 = a3[2][r], l3 = a3[3][r];
                float mx = fmaxf(fmaxf(l0, l1), fmaxf(l2, l3));
#pragma unroll
                for (int o2 = 8; o2; o2 >>= 1) mx = fmaxf(mx, __shfl_xor(mx, o2));
                float sm = __expf(l0 - mx) + __expf(l1 - mx) +
                           __expf(l2 - mx) + __expf(l3 - mx);
#pragma unroll
                for (int o2 = 8; o2; o2 >>= 1) sm += __shfl_xor(sm, o2);
                float lse = mx + __logf(sm);
                if (q == r && base + r < nH) {           // quad r writes row r (rowv matches rsel)
                    out[rowv * 64 + n] = l0 - lse;
                    out[rowv * 64 + 16 + n] = l1 - lse;
                    out[rowv * 64 + 32 + n] = l2 - lse;
                    out[rowv * 64 + 48 + n] = l3 - lse;
                }
            }
        }
    }

    // ---- light rows: 16 rows/iteration via MFMA; reverse wave order ----
    if (nL > 0) {
        short* cmbL = sCmb + wave * 640;
        f4 bcV[2], btV[4];
#pragma unroll
        for (int t = 0; t < 2; ++t) { float bv = bc[t * 16 + n]; bcV[t] = f4{bv, bv, bv, bv}; }
#pragma unroll
        for (int t = 0; t < 4; ++t) { float bv = bt[t * 16 + n]; btV[t] = f4{bv, bv, bv, bv}; }
        const int lgw = NW - 1 - gw;
#pragma unroll 1
        for (int base = lgw * 16; base < nL; base += NW * 16) {
            int idx = min(base + lane, nL - 1);
            int sl = 0;
#pragma unroll
            for (int b2 = 0; b2 < 32; ++b2) sl += (__shfl(liIncl, b2) <= idx) ? 1 : 0;
            const int lrow = listL[sl * 1024 + idx - __shfl(liExcl, sl)];
            const int ltok = x[lrow * 16];
            int t8 = __shfl(ltok, n);
            const f4* ep = (const f4*)&emb[t8 * 32 + q * 8];
            short8 aE = cvt8(ep[0], ep[1]);
            // comb = relu(emb @ Wc1^T + bc) -> LDS [16][40]
#pragma unroll
            for (int tl2 = 0; tl2 < 2; ++tl2) {
                short8 b1 = *(const short8*)&wc1[(tl2 * 16 + n) * 32 + q * 8];
                f4 t0 = MFMA16(aE, b1, bcV[tl2]);
#pragma unroll
                for (int r = 0; r < 4; ++r)
                    cmbL[(q * 4 + r) * 40 + tl2 * 16 + n] = f2bf(fmaxf(t0[r], 0.f));
            }
            CFENCE();
            short8 cA = *(const short8*)&cmbL[n * 40 + q * 8];
            f4 a3[4];
#pragma unroll
            for (int tl3 = 0; tl3 < 4; ++tl3) {
                short8 bW = *(const short8*)&wth[(tl3 * 16 + n) * 32 + q * 8];
                a3[tl3] = MFMA16(cA, bW, btV[tl3]);
            }
#pragma unroll
            for (int r = 0; r < 4; ++r) {
                float l0 = a3[0][r], l1 = a3[1][r], l2 = a3[2][r], l3 = a3[3][r];
                float mx = fmaxf(fmaxf(l0, l1), fmaxf(l2, l3));
#pragma unroll
                for (int o2 = 8; o2; o2 >>= 1) mx = fmaxf(mx, __shfl_xor(mx, o2));
                float sm = __expf(l0 - mx) + __expf(l1 - mx) +
                           __expf(l2 - mx) + __expf(l3 - mx);
#pragma unroll
                for (int o2 = 8; o2; o2 >>= 1) sm += __shfl_xor(sm, o2);
                float lse = mx + __logf(sm);
                int rowO = __shfl(lrow, q * 4 + r);
                if (base + q * 4 + r < nL) {
                    out[rowO * 64 + n] = l0 - lse;
                    out[rowO * 64 + 16 + n] = l1 - lse;
                    out[rowO * 64 + 32 + n] = l2 - lse;
                    out[rowO * 64 + 48 + n] = l3 - lse;
                }
            }
            CFENCE();
        }
    }
}

// ---------------- fallback (small ws): monolithic fp32 kernel ----------------
__global__ __launch_bounds__(512) void tagger_fallback(
    const int* __restrict__ x, const int* __restrict__ s, const float* __restrict__ emb,
    const float* __restrict__ Wih, const float* __restrict__ Whh,
    const float* __restrict__ bih, const float* __restrict__ bhh,
    const float* __restrict__ h0, const float* __restrict__ c0,
    const float* __restrict__ Wc, const float* __restrict__ bc,
    const float* __restrict__ Wt, const float* __restrict__ bt,
    float* __restrict__ out) {
    __shared__ float4 WhhP[4096];
    __shared__ float combBuf[8][128];
    for (int i = threadIdx.x; i < 4096; i += 512) {
        int k = i & 63, jj = i >> 6;
        WhhP[k * 64 + jj] = make_float4(Whh[jj * 64 + k], Whh[(jj + 64) * 64 + k],
                                        Whh[(jj + 128) * 64 + k], Whh[(jj + 192) * 64 + k]);
    }
    __syncthreads();
    const int wave = threadIdx.x >> 6, j = threadIdx.x & 63, jm = j & 31;
    const int b = blockIdx.x * 8 + wave;
    const int sv = s[b];
    const int* xb = x + b * NT;
    const float bcj = bc[jm];
    auto rc_val = [&](int tok) -> float {
        float r = 0.f;
#pragma unroll
        for (int k = 0; k < 32; ++k) r = fmaf(emb[tok * NE + k], Wc[jm * 96 + k], r);
        return r;
    };
    float comb4;
    if (sv >= 4) {
        const float h0j = h0[j], c0j = c0[j];
        float4 bsj = make_float4(bih[j] + bhh[j], bih[j + 64] + bhh[j + 64],
                                 bih[j + 128] + bhh[j + 128], bih[j + 192] + bhh[j + 192]);
#pragma unroll 1
        for (int node = 0; node < 4; ++node) {
            float h = h0j, c = c0j;
#pragma unroll 1
            for (int t = 0; t < 4; ++t) {
                int tok = xb[node * 4 + t];
                float4 p = bsj;
#pragma unroll
                for (int k = 0; k < 32; ++k) {
                    float e = emb[tok * NE + k];
                    p.x = fmaf(e, Wih[j * 32 + k], p.x);
                    p.y = fmaf(e, Wih[(j + 64) * 32 + k], p.y);
                    p.z = fmaf(e, Wih[(j + 128) * 32 + k], p.z);
                    p.w = fmaf(e, Wih[(j + 192) * 32 + k], p.w);
                }
                float4 a = make_float4(0.f, 0.f, 0.f, 0.f);
#pragma unroll
                for (int k = 0; k < 64; ++k) {
                    float hk = __shfl(h, k);
                    float4 w = WhhP[k * 64 + j];
                    a.x = fmaf(hk, w.x, a.x); a.y = fmaf(hk, w.y, a.y);
                    a.z = fmaf(hk, w.z, a.z); a.w = fmaf(hk, w.w, a.w);
                }
                a.x += p.x; a.y += p.y; a.z += p.z; a.w += p.w;
                float ig = sigm_(a.x), fg = sigm_(a.y), gg = tanh2_(a.z), og = sigm_(a.w);
                c = fmaf(fg, c, ig * gg);
                h = og * tanh2_(c);
            }
            float last = fmaxf(h, 0.f);
            float acc = rc_val(xb[node * 4]) + bcj;
#pragma unroll
            for (int k = 0; k < 64; ++k)
                acc = fmaf(__shfl(last, k), Wc[jm * 96 + 32 + k], acc);
            if (j < 32) combBuf[wave][node * 32 + j] = fmaxf(acc, 0.f);
        }
        LDSSYNC();
        float h = h0j, c = c0j;
#pragma unroll 1
        for (int t = 0; t < 4; ++t) {
            float4 a = make_float4(0.f, 0.f, 0.f, 0.f);
#pragma unroll
            for (int k = 0; k < 32; ++k) {
                float ck = combBuf[wave][t * 32 + k];
                a.x = fmaf(ck, Wih[j * 32 + k], a.x);
                a.y = fmaf(ck, Wih[(j + 64) * 32 + k], a.y);
                a.z = fmaf(ck, Wih[(j + 128) * 32 + k], a.z);
                a.w = fmaf(ck, Wih[(j + 192) * 32 + k], a.w);
            }
#pragma unroll
            for (int k = 0; k < 64; ++k) {
                float hk = __shfl(h, k);
                float4 w = WhhP[k * 64 + j];
                a.x = fmaf(hk, w.x, a.x); a.y = fmaf(hk, w.y, a.y);
                a.z = fmaf(hk, w.z, a.z); a.w = fmaf(hk, w.w, a.w);
            }
            a.x += bih[j] + bhh[j]; a.y += bih[j + 64] + bhh[j + 64];
            a.z += bih[j + 128] + bhh[j + 128]; a.w += bih[j + 192] + bhh[j + 192];
            float ig = sigm_(a.x), fg = sigm_(a.y), gg = tanh2_(a.z), og = sigm_(a.w);
            c = fmaf(fg, c, ig * gg);
            h = og * tanh2_(c);
        }
        float last = fmaxf(h, 0.f);
        float acc = rc_val(xb[0]) + bcj;
#pragma unroll
        for (int k = 0; k < 64; ++k)
            acc = fmaf(__shfl(last, k), Wc[jm * 96 + 32 + k], acc);
        comb4 = fmaxf(acc, 0.f);
    } else {
        comb4 = fmaxf(rc_val(xb[0]) + bcj, 0.f);
    }
    float logit = bt[j];
    const float* wtr = Wt + j * 32;
#pragma unroll
    for (int k = 0; k < 32; ++k) logit = fmaf(__shfl(comb4, k), wtr[k], logit);
    float mx = logit;
#pragma unroll
    for (int off = 32; off; off >>= 1) mx = fmaxf(mx, __shfl_xor(mx, off));
    float ex = __expf(logit - mx);
    float sum = ex;
#pragma unroll
    for (int off = 32; off; off >>= 1) sum += __shfl_xor(sum, off);
    out[b * 64 + j] = logit - mx - __logf(sum);
}

extern "C" void kernel_launch(void* const* d_in, const int* in_sizes, int n_in,
                              void* d_out, int out_size, void* d_ws, size_t ws_size,
                              hipStream_t stream) {
    const int* x = (const int*)d_in[0];
    const int* s = (const int*)d_in[1];
    const float* emb = (const float*)d_in[2];
    const float* Wih = (const float*)d_in[3];
    const float* Whh = (const float*)d_in[4];
    const float* bih = (const float*)d_in[5];
    const float* bhh = (const float*)d_in[6];
    const float* h0 = (const float*)d_in[7];
    const float* c0 = (const float*)d_in[8];
    const float* Wc = (const float*)d_in[9];
    const float* bc = (const float*)d_in[10];
    const float* Wt = (const float*)d_in[11];
    const float* bt = (const float*)d_in[12];
    float* out = (float*)d_out;

    auto al16 = [](size_t v) { return (v + 15) & ~(size_t)15; };
    size_t off = 0;
    size_t oWpack = off; off = al16(off + (size_t)28672 * 2);
    size_t oWc1 = off;   off = al16(off + 1024 * 2);
    size_t oWc2 = off;   off = al16(off + 2048 * 2);
    size_t oWt = off;    off = al16(off + 2048 * 2);
    size_t oBsum = off;  off = al16(off + 256 * 4);
    size_t oCH = off;    off = al16(off + 32 * 4);
    size_t oListH = off; off = al16(off + (size_t)NB * 4);
    size_t oListL = off; off = al16(off + (size_t)NB * 4);
    size_t need = off;

    char* ws = (char*)d_ws;
    if (ws_size >= need) {
        short* wpack = (short*)(ws + oWpack);
        short* wc1 = (short*)(ws + oWc1);
        short* wc2 = (short*)(ws + oWc2);
        short* wth = (short*)(ws + oWt);
        float* bsum = (float*)(ws + oBsum);
        int* cHp = (int*)(ws + oCH);
        int* listH = (int*)(ws + oListH);
        int* listL = (int*)(ws + oListL);

        prep_kernel<<<dim3(33), dim3(512), 0, stream>>>(
            s, Wih, Whh, bih, bhh, Wc, Wt, wpack, wc1, wc2, wth, bsum,
            cHp, listH, listL);
        main_kernel<<<dim3(1024), dim3(256), 0, stream>>>(
            x, emb, h0, c0, bc, bt, bsum, wpack, wc1, wc2, wth,
            cHp, listH, listL, out);
    } else {
        tagger_fallback<<<dim3(4096), dim3(512), 0, stream>>>(
            x, s, emb, Wih, Whh, bih, bhh, h0, c0, Wc, bc, Wt, bt, out);
    }
}

// Round 11
// 152.099 us; speedup vs baseline: 1.8677x; 1.7358x over previous
//
#include <hip/hip_runtime.h>

// Problem constants
#define NB 32768
#define NT 16
#define NV 32001   // V+1
#define NE 32
#define NTAGS 64

typedef __attribute__((ext_vector_type(8))) short short8;   // 8 bf16 (4 VGPR)
typedef __attribute__((ext_vector_type(4))) float f4;       // MFMA acc

#define MFMA16(a, b, c) __builtin_amdgcn_mfma_f32_16x16x32_bf16(a, b, c, 0, 0, 0)
// DS ops are in-order within a wave -> compiler-only fence suffices for same-wave LDS RAW
#define CFENCE() asm volatile("" ::: "memory")
#define LDSSYNC() asm volatile("s_waitcnt lgkmcnt(0)" ::: "memory")

__device__ __forceinline__ float sigm_(float x) {
    return __builtin_amdgcn_rcpf(1.0f + __expf(-x));
}
__device__ __forceinline__ float tanh2_(float x) {  // 2*sigm(2x)-1
    float e = __expf(-2.0f * x);
    return fmaf(2.0f, __builtin_amdgcn_rcpf(1.0f + e), -1.0f);
}
__device__ __forceinline__ short f2bf(float x) {  // RNE float->bf16 bits
    union { float f; unsigned u; } v; v.f = x;
    unsigned r = v.u + 0x7fffu + ((v.u >> 16) & 1u);
    return (short)(r >> 16);
}

// ---------------- K1: classify (32 slabs, no atomics) + emb->bf16 + weight pack ----------------
__global__ __launch_bounds__(1024) void classify_prep(
    const int* __restrict__ s, const float* __restrict__ emb,
    const float* __restrict__ Wih, const float* __restrict__ Whh,
    const float* __restrict__ bih, const float* __restrict__ bhh,
    const float* __restrict__ Wc, const float* __restrict__ Wt,
    short* __restrict__ embH, short* __restrict__ wpack, short* __restrict__ wc1,
    short* __restrict__ wc2, short* __restrict__ wth, float* __restrict__ bsum,
    int* __restrict__ cH, int* __restrict__ listH, int* __restrict__ listL) {
    __shared__ int wbH[16], wbL[16];
    const int tid = threadIdx.x, b = blockIdx.x;
    if (b < 32) {
        const int row = b * 1024 + tid;
        const bool heavy = s[row] >= 4;
        unsigned long long mk = __ballot(heavy);
        const int wv = tid >> 6, ln = tid & 63;
        if (ln == 0) wbH[wv] = __popcll(mk);
        __syncthreads();
        if (tid == 0) {
            int tH = 0, tL = 0;
#pragma unroll
            for (int i = 0; i < 16; ++i) {
                int ch = wbH[i];
                wbH[i] = tH; wbL[i] = tL;
                tH += ch; tL += 64 - ch;
            }
            cH[b] = tH;
        }
        __syncthreads();
        unsigned long long ltm = (1ull << ln) - 1ull;
        if (heavy) listH[b * 1024 + wbH[wv] + __popcll(mk & ltm)] = row;
        else       listL[b * 1024 + wbL[wv] + __popcll((~mk) & ltm)] = row;
    }
    // emb -> bf16 (striped over all 256 blocks)
    for (int i = b * 1024 + tid; i < NV * NE; i += 262144) embH[i] = f2bf(emb[i]);
    if (b == 32) {  // weight pack
        for (int t = tid; t < 18432; t += 1024) {
            int r = t / 72, c = t % 72;
            wpack[t] = f2bf(c < 64 ? Whh[r * 64 + c] : 0.f);
        }
        for (int t = tid; t < 10240; t += 1024) {
            int r = t / 40, c = t % 40;
            wpack[18432 + t] = f2bf(c < 32 ? Wih[r * 32 + c] : 0.f);
        }
        if (tid < 1024) { int r = tid >> 5, c = tid & 31; wc1[tid] = f2bf(Wc[r * 96 + c]); }
        for (int t = tid; t < 2048; t += 1024) {
            int r = t >> 6, c = t & 63;
            wc2[t] = f2bf(Wc[r * 96 + 32 + c]);
        }
        for (int t = tid; t < 2048; t += 1024) {
            int r = t >> 5, c = t & 31;
            wth[t] = f2bf(Wt[r * 32 + c]);
        }
        if (tid < 256) bsum[tid] = bih[tid] + bhh[tid];
    }
}

// ---------------- K2: fused main — heavy (4 rows/wave, MFMA) + light (16 rows/iter, MFMA) --------
// __launch_bounds__(256, 2): r7-proven VGPR budget (alloc ~128, NO scratch spill). The (256,3)
// variants (r8/r10) capped VGPR at 84 -> 40-178 MB of spill traffic. Heavy waves are work-capped
// at 2048 (8/CU) so min-waves=3 buys nothing; LDS 52.7 KB still allows 3 blocks/CU at VGPR<=170.
__global__ __launch_bounds__(256, 2) void main_fused(
    const int* __restrict__ x, const float* __restrict__ emb,
    const float* __restrict__ h0, const float* __restrict__ c0,
    const float* __restrict__ Wc, const float* __restrict__ bc,
    const float* __restrict__ Wt, const float* __restrict__ bt,
    const float* __restrict__ bsum,
    const short* __restrict__ wpack, const short* __restrict__ wc1,
    const short* __restrict__ wc2, const short* __restrict__ wth,
    const short* __restrict__ embH, const int* __restrict__ cH,
    const int* __restrict__ listH, const int* __restrict__ listL,
    float* __restrict__ out) {
    __shared__ __align__(16) short sWhh[18432];      // 36 KB [256][72] bf16 (FULL: 2304 uint4)
    __shared__ __align__(16) short sHA[4][16 * 72];  // per-wave h, A-frag layout (bf16)
    __shared__ __align__(16) short sCmb[4][16 * 40]; // per-wave comb[(node*4+row)][40] / light comb
    __shared__ __align__(16) short sC4[4][4 * 40];   // per-wave comb4[row][40]

    const int tid = threadIdx.x, wave = tid >> 6, lane = tid & 63;
    const int q = lane >> 4, n = lane & 15;
    const int NW = gridDim.x * 4;  // 3072
    const int gw = blockIdx.x * 4 + wave;

    // 32-slab prefix scan (per wave, shfl) — before staging so light-only blocks skip it
    int cs = (lane < 32) ? cH[lane] : 0;
    int v = cs;
#pragma unroll
    for (int o = 1; o < 32; o <<= 1) { int t2 = __shfl_up(v, o); if (lane >= o) v += t2; }
    const int vIncl = v, vExcl = v - cs;
    const int nH = __shfl(vIncl, 31);
    const int nL = NB - nH;
    const int liIncl = (lane + 1) * 1024 - vIncl;  // light prefixes (lane<32)
    const int liExcl = lane * 1024 - vExcl;
    const int nHW = (nH + 3) >> 2;                 // heavy wave count

    if ((int)blockIdx.x * 4 < nHW) {  // block-uniform: only heavy blocks stage Whh
        for (int i = tid; i < 2304; i += 256)
            ((uint4*)sWhh)[i] = ((const uint4*)wpack)[i];
        __syncthreads();
    }

    if (gw < nHW) {
        short* hA = sHA[wave];
        short* cmb = sCmb[wave];
        short* c4 = sC4[wave];
        const short* wihG = wpack + 18432;

        // loop-invariant Wih fragments in registers (64 VGPR) — no per-step global loads
        short8 wihR[16];
#pragma unroll
        for (int tl = 0; tl < 16; ++tl)
            wihR[tl] = *(const short8*)&wihG[(tl * 16 + n) * 40 + q * 8];

        float bias16[16];
#pragma unroll
        for (int tl = 0; tl < 16; ++tl) bias16[tl] = bsum[tl * 16 + n];
        float bc2[2] = {bc[n], bc[16 + n]};
        float bt4[4] = {bt[n], bt[16 + n], bt[32 + n], bt[48 + n]};
        float c0v[4]; short h0b[4];
#pragma unroll
        for (int u = 0; u < 4; ++u) { c0v[u] = c0[u * 16 + n]; h0b[u] = f2bf(h0[u * 16 + n]); }

        const f4 zero4 = {0.f, 0.f, 0.f, 0.f};
        f4 acc[16];
        float cst[4][4];

        auto initSt = [&]() {
#pragma unroll
            for (int u = 0; u < 4; ++u) {
                short hb = h0b[u];
#pragma unroll
                for (int r = 0; r < 4; ++r) {
                    cst[r][u] = c0v[u];
                    hA[(q * 4 + r) * 72 + u * 16 + n] = hb;
                }
            }
            CFENCE();
        };
        auto doStep = [&](short8 aP, bool doRelu) {
            short8 ah0 = *(const short8*)&hA[n * 72 + q * 8];
            short8 ah1 = *(const short8*)&hA[n * 72 + 32 + q * 8];
#pragma unroll
            for (int tl = 0; tl < 16; ++tl) acc[tl] = MFMA16(aP, wihR[tl], zero4);
#pragma unroll
            for (int tl = 0; tl < 16; ++tl) {
                const short* rbp = &sWhh[(tl * 16 + n) * 72 + q * 8];
                f4 t0 = acc[tl];
                t0 = MFMA16(ah0, *(const short8*)rbp, t0);
                t0 = MFMA16(ah1, *(const short8*)(rbp + 32), t0);
                acc[tl] = t0;
            }
            CFENCE();
#pragma unroll
            for (int u = 0; u < 4; ++u)
#pragma unroll
                for (int r = 0; r < 4; ++r) {
                    float ip = acc[u][r] + bias16[u];
                    float fp = acc[4 + u][r] + bias16[4 + u];
                    float gp = acc[8 + u][r] + bias16[8 + u];
                    float op = acc[12 + u][r] + bias16[12 + u];
                    float cc = fmaf(sigm_(fp), cst[r][u], sigm_(ip) * tanh2_(gp));
                    cst[r][u] = cc;
                    float hh = sigm_(op) * tanh2_(cc);
                    if (doRelu) hh = fmaxf(hh, 0.f);
                    hA[(q * 4 + r) * 72 + u * 16 + n] = f2bf(hh);
                }
            CFENCE();
        };
        // comb = relu([root,last]@Wc^T+bc) for 16 units; D unit m=q*4+r
        auto combMM = [&](short8 aroot, short* dst, int strideSel) {
            short8 lh0 = *(const short8*)&hA[n * 72 + q * 8];
            short8 lh1 = *(const short8*)&hA[n * 72 + 32 + q * 8];
#pragma unroll
            for (int tl2 = 0; tl2 < 2; ++tl2) {
                float bv = bc2[tl2];
                f4 t0 = {bv, bv, bv, bv};
                short8 b1 = *(const short8*)&wc1[(tl2 * 16 + n) * 32 + q * 8];
                t0 = MFMA16(aroot, b1, t0);
                const short* rbp = &wc2[(tl2 * 16 + n) * 64 + q * 8];
                t0 = MFMA16(lh0, *(const short8*)rbp, t0);
                t0 = MFMA16(lh1, *(const short8*)(rbp + 32), t0);
#pragma unroll
                for (int r = 0; r < 4; ++r) {
                    int ui = strideSel ? (q * 4 + r) : r;  // phase2: quads duplicate rows
                    dst[ui * 40 + tl2 * 16 + n] = f2bf(fmaxf(t0[r], 0.f));
                }
            }
            CFENCE();
        };

#pragma unroll 1
        for (int it = gw; it * 4 < nH; it += NW) {
            const int base = it * 4;
            int idxq = min(base + q, nH - 1);
            int sl = 0;
#pragma unroll
            for (int b2 = 0; b2 < 32; ++b2) sl += (__shfl(vIncl, b2) <= idxq) ? 1 : 0;
            const int row = listH[sl * 1024 + idxq - __shfl(vExcl, sl)];
            const int tokAll = x[row * 16 + n];  // lane (q,n) holds x[row_q][n]
            const int liBase = (n & 3) * 16 + (n >> 2) * 4;  // unit n: row n&3, node n>>2

            // ---- phase 1: 4 rows x 4 nodes in the 16 units, 4 steps ----
            initSt();
            int tok = __shfl(tokAll, liBase);
            short8 aNext = *(const short8*)&embH[tok * 32 + q * 8];
            const short8 aRoot = aNext;
#pragma unroll 1
            for (int t = 0; t < 4; ++t) {
                short8 aP = aNext;
                if (t < 3) {
                    int tk2 = __shfl(tokAll, liBase + t + 1);
                    aNext = *(const short8*)&embH[tk2 * 32 + q * 8];
                }
                doStep(aP, t == 3);  // step 3 writes relu(h) = "last"
            }
            combMM(aRoot, cmb, 1);   // cmb[(node*4+row)][40]

            // ---- phase 2: node 4 (children = comb_0..3), rows duplicated x4 ----
            initSt();
            int tokR = __shfl(tokAll, (n & 3) * 16);
            short8 aR4 = *(const short8*)&embH[tokR * 32 + q * 8];
#pragma unroll 1
            for (int t = 0; t < 4; ++t) {
                short8 aC = *(const short8*)&cmb[(t * 4 + (n & 3)) * 40 + q * 8];
                doStep(aC, t == 3);
            }
            combMM(aR4, c4, 0);      // c4[row][40] (4 quads write identical)

            // ---- phase 3: logits + log_softmax for 4 rows ----
            short8 cA = *(const short8*)&c4[(n & 3) * 40 + q * 8];
            f4 a3[4];
#pragma unroll
            for (int tl3 = 0; tl3 < 4; ++tl3) {
                float bv = bt4[tl3];
                f4 t0 = {bv, bv, bv, bv};
                short8 bW = *(const short8*)&wth[(tl3 * 16 + n) * 32 + q * 8];
                a3[tl3] = MFMA16(cA, bW, t0);
            }
#pragma unroll
            for (int r = 0; r < 4; ++r) {
                float l0 = a3[0][r], l1 = a3[1][r], l2 = a3[2][r], l3 = a3[3][r];
                float mx = fmaxf(fmaxf(l0, l1), fmaxf(l2, l3));
#pragma unroll
                for (int o2 = 8; o2; o2 >>= 1) mx = fmaxf(mx, __shfl_xor(mx, o2));
                float sm = __expf(l0 - mx) + __expf(l1 - mx) +
                           __expf(l2 - mx) + __expf(l3 - mx);
#pragma unroll
                for (int o2 = 8; o2; o2 >>= 1) sm += __shfl_xor(sm, o2);
                float lse = mx + __logf(sm);
                if (q == r && base + r < nH) {
                    out[row * 64 + n] = l0 - lse;
                    out[row * 64 + 16 + n] = l1 - lse;
                    out[row * 64 + 32 + n] = l2 - lse;
                    out[row * 64 + 48 + n] = l3 - lse;
                }
            }
        }
    }

    // ---- light rows: 16 rows/iteration via MFMA; reverse wave order ----
    if (nL > 0) {
        short* cmbL = sCmb[wave];  // reused (heavy phase done for this wave)
        f4 bcV[2], btV[4];
#pragma unroll
        for (int t = 0; t < 2; ++t) { float bv = bc[t * 16 + n]; bcV[t] = f4{bv, bv, bv, bv}; }
#pragma unroll
        for (int t = 0; t < 4; ++t) { float bv = bt[t * 16 + n]; btV[t] = f4{bv, bv, bv, bv}; }
        const int lgw = NW - 1 - gw;
#pragma unroll 1
        for (int base = lgw * 16; base < nL; base += NW * 16) {
            int idx = min(base + lane, nL - 1);
            int sl = 0;
#pragma unroll
            for (int b2 = 0; b2 < 32; ++b2) sl += (__shfl(liIncl, b2) <= idx) ? 1 : 0;
            const int lrow = listL[sl * 1024 + idx - __shfl(liExcl, sl)];
            const int ltok = x[lrow * 16];
            short8 aE = *(const short8*)&embH[__shfl(ltok, n) * 32 + q * 8];
            // comb = relu(emb @ Wc1^T + bc) -> LDS [16][40]
#pragma unroll
            for (int tl2 = 0; tl2 < 2; ++tl2) {
                short8 b1 = *(const short8*)&wc1[(tl2 * 16 + n) * 32 + q * 8];
                f4 t0 = MFMA16(aE, b1, bcV[tl2]);
#pragma unroll
                for (int r = 0; r < 4; ++r)
                    cmbL[(q * 4 + r) * 40 + tl2 * 16 + n] = f2bf(fmaxf(t0[r], 0.f));
            }
            CFENCE();
            short8 cA = *(const short8*)&cmbL[n * 40 + q * 8];
            f4 a3[4];
#pragma unroll
            for (int tl3 = 0; tl3 < 4; ++tl3) {
                short8 bW = *(const short8*)&wth[(tl3 * 16 + n) * 32 + q * 8];
                a3[tl3] = MFMA16(cA, bW, btV[tl3]);
            }
#pragma unroll
            for (int r = 0; r < 4; ++r) {
                float l0 = a3[0][r], l1 = a3[1][r], l2 = a3[2][r], l3 = a3[3][r];
                float mx = fmaxf(fmaxf(l0, l1), fmaxf(l2, l3));
#pragma unroll
                for (int o2 = 8; o2; o2 >>= 1) mx = fmaxf(mx, __shfl_xor(mx, o2));
                float sm = __expf(l0 - mx) + __expf(l1 - mx) +
                           __expf(l2 - mx) + __expf(l3 - mx);
#pragma unroll
                for (int o2 = 8; o2; o2 >>= 1) sm += __shfl_xor(sm, o2);
                float lse = mx + __logf(sm);
                int rowO = __shfl(lrow, q * 4 + r);
                if (base + q * 4 + r < nL) {
                    out[rowO * 64 + n] = l0 - lse;
                    out[rowO * 64 + 16 + n] = l1 - lse;
                    out[rowO * 64 + 32 + n] = l2 - lse;
                    out[rowO * 64 + 48 + n] = l3 - lse;
                }
            }
            CFENCE();
        }
    }
}

// ---------------- fallback (small ws): monolithic fp32 kernel ----------------
__global__ __launch_bounds__(512) void tagger_fallback(
    const int* __restrict__ x, const int* __restrict__ s, const float* __restrict__ emb,
    const float* __restrict__ Wih, const float* __restrict__ Whh,
    const float* __restrict__ bih, const float* __restrict__ bhh,
    const float* __restrict__ h0, const float* __restrict__ c0,
    const float* __restrict__ Wc, const float* __restrict__ bc,
    const float* __restrict__ Wt, const float* __restrict__ bt,
    float* __restrict__ out) {
    __shared__ float4 WhhP[4096];
    __shared__ float combBuf[8][128];
    for (int i = threadIdx.x; i < 4096; i += 512) {
        int k = i & 63, jj = i >> 6;
        WhhP[k * 64 + jj] = make_float4(Whh[jj * 64 + k], Whh[(jj + 64) * 64 + k],
                                        Whh[(jj + 128) * 64 + k], Whh[(jj + 192) * 64 + k]);
    }
    __syncthreads();
    const int wave = threadIdx.x >> 6, j = threadIdx.x & 63, jm = j & 31;
    const int b = blockIdx.x * 8 + wave;
    const int sv = s[b];
    const int* xb = x + b * NT;
    const float bcj = bc[jm];
    auto rc_val = [&](int tok) -> float {
        float r = 0.f;
#pragma unroll
        for (int k = 0; k < 32; ++k) r = fmaf(emb[tok * NE + k], Wc[jm * 96 + k], r);
        return r;
    };
    float comb4;
    if (sv >= 4) {
        const float h0j = h0[j], c0j = c0[j];
        float4 bsj = make_float4(bih[j] + bhh[j], bih[j + 64] + bhh[j + 64],
                                 bih[j + 128] + bhh[j + 128], bih[j + 192] + bhh[j + 192]);
#pragma unroll 1
        for (int node = 0; node < 4; ++node) {
            float h = h0j, c = c0j;
#pragma unroll 1
            for (int t = 0; t < 4; ++t) {
                int tok = xb[node * 4 + t];
                float4 p = bsj;
#pragma unroll
                for (int k = 0; k < 32; ++k) {
                    float e = emb[tok * NE + k];
                    p.x = fmaf(e, Wih[j * 32 + k], p.x);
                    p.y = fmaf(e, Wih[(j + 64) * 32 + k], p.y);
                    p.z = fmaf(e, Wih[(j + 128) * 32 + k], p.z);
                    p.w = fmaf(e, Wih[(j + 192) * 32 + k], p.w);
                }
                float4 a = make_float4(0.f, 0.f, 0.f, 0.f);
#pragma unroll
                for (int k = 0; k < 64; ++k) {
                    float hk = __shfl(h, k);
                    float4 w = WhhP[k * 64 + j];
                    a.x = fmaf(hk, w.x, a.x); a.y = fmaf(hk, w.y, a.y);
                    a.z = fmaf(hk, w.z, a.z); a.w = fmaf(hk, w.w, a.w);
                }
                a.x += p.x; a.y += p.y; a.z += p.z; a.w += p.w;
                float ig = sigm_(a.x), fg = sigm_(a.y), gg = tanh2_(a.z), og = sigm_(a.w);
                c = fmaf(fg, c, ig * gg);
                h = og * tanh2_(c);
            }
            float last = fmaxf(h, 0.f);
            float acc = rc_val(xb[node * 4]) + bcj;
#pragma unroll
            for (int k = 0; k < 64; ++k)
                acc = fmaf(__shfl(last, k), Wc[jm * 96 + 32 + k], acc);
            if (j < 32) combBuf[wave][node * 32 + j] = fmaxf(acc, 0.f);
        }
        LDSSYNC();
        float h = h0j, c = c0j;
#pragma unroll 1
        for (int t = 0; t < 4; ++t) {
            float4 a = make_float4(0.f, 0.f, 0.f, 0.f);
#pragma unroll
            for (int k = 0; k < 32; ++k) {
                float ck = combBuf[wave][t * 32 + k];
                a.x = fmaf(ck, Wih[j * 32 + k], a.x);
                a.y = fmaf(ck, Wih[(j + 64) * 32 + k], a.y);
                a.z = fmaf(ck, Wih[(j + 128) * 32 + k], a.z);
                a.w = fmaf(ck, Wih[(j + 192) * 32 + k], a.w);
            }
#pragma unroll
            for (int k = 0; k < 64; ++k) {
                float hk = __shfl(h, k);
                float4 w = WhhP[k * 64 + j];
                a.x = fmaf(hk, w.x, a.x); a.y = fmaf(hk, w.y, a.y);
                a.z = fmaf(hk, w.z, a.z); a.w = fmaf(hk, w.w, a.w);
            }
            a.x += bih[j] + bhh[j]; a.y += bih[j + 64] + bhh[j + 64];
            a.z += bih[j + 128] + bhh[j + 128]; a.w += bih[j + 192] + bhh[j + 192];
            float ig = sigm_(a.x), fg = sigm_(a.y), gg = tanh2_(a.z), og = sigm_(a.w);
            c = fmaf(fg, c, ig * gg);
            h = og * tanh2_(c);
        }
        float last = fmaxf(h, 0.f);
        float acc = rc_val(xb[0]) + bcj;
#pragma unroll
        for (int k = 0; k < 64; ++k)
            acc = fmaf(__shfl(last, k), Wc[jm * 96 + 32 + k], acc);
        comb4 = fmaxf(acc, 0.f);
    } else {
        comb4 = fmaxf(rc_val(xb[0]) + bcj, 0.f);
    }
    float logit = bt[j];
    const float* wtr = Wt + j * 32;
#pragma unroll
    for (int k = 0; k < 32; ++k) logit = fmaf(__shfl(comb4, k), wtr[k], logit);
    float mx = logit;
#pragma unroll
    for (int off = 32; off; off >>= 1) mx = fmaxf(mx, __shfl_xor(mx, off));
    float ex = __expf(logit - mx);
    float sum = ex;
#pragma unroll
    for (int off = 32; off; off >>= 1) sum += __shfl_xor(sum, off);
    out[b * 64 + j] = logit - mx - __logf(sum);
}

extern "C" void kernel_launch(void* const* d_in, const int* in_sizes, int n_in,
                              void* d_out, int out_size, void* d_ws, size_t ws_size,
                              hipStream_t stream) {
    const int* x = (const int*)d_in[0];
    const int* s = (const int*)d_in[1];
    const float* emb = (const float*)d_in[2];
    const float* Wih = (const float*)d_in[3];
    const float* Whh = (const float*)d_in[4];
    const float* bih = (const float*)d_in[5];
    const float* bhh = (const float*)d_in[6];
    const float* h0 = (const float*)d_in[7];
    const float* c0 = (const float*)d_in[8];
    const float* Wc = (const float*)d_in[9];
    const float* bc = (const float*)d_in[10];
    const float* Wt = (const float*)d_in[11];
    const float* bt = (const float*)d_in[12];
    float* out = (float*)d_out;

    auto al16 = [](size_t v) { return (v + 15) & ~(size_t)15; };
    size_t off = 0;
    size_t oWpack = off; off = al16(off + (size_t)28672 * 2);  // WhhHi[256x72]+WihHi[256x40]
    size_t oWc1 = off;   off = al16(off + 1024 * 2);
    size_t oWc2 = off;   off = al16(off + 2048 * 2);
    size_t oWt = off;    off = al16(off + 2048 * 2);
    size_t oBsum = off;  off = al16(off + 256 * 4);
    size_t oEmbH = off;  off = al16(off + (size_t)NV * NE * 2);
    size_t oCH = off;    off = al16(off + 32 * 4);
    size_t oListH = off; off = al16(off + (size_t)NB * 4);
    size_t oListL = off; off = al16(off + (size_t)NB * 4);
    size_t need = off;

    char* ws = (char*)d_ws;
    if (ws_size >= need) {
        short* wpack = (short*)(ws + oWpack);
        short* wc1 = (short*)(ws + oWc1);
        short* wc2 = (short*)(ws + oWc2);
        short* wth = (short*)(ws + oWt);
        float* bsum = (float*)(ws + oBsum);
        short* embH = (short*)(ws + oEmbH);
        int* cHp = (int*)(ws + oCH);
        int* listH = (int*)(ws + oListH);
        int* listL = (int*)(ws + oListL);

        classify_prep<<<dim3(256), dim3(1024), 0, stream>>>(
            s, emb, Wih, Whh, bih, bhh, Wc, Wt,
            embH, wpack, wc1, wc2, wth, bsum, cHp, listH, listL);
        main_fused<<<dim3(768), dim3(256), 0, stream>>>(
            x, emb, h0, c0, Wc, bc, Wt, bt, bsum,
            wpack, wc1, wc2, wth, embH, cHp, listH, listL, out);
    } else {
        tagger_fallback<<<dim3(4096), dim3(512), 0, stream>>>(
            x, s, emb, Wih, Whh, bih, bhh, h0, c0, Wc, bc, Wt, bt, out);
    }
}